// Round 12
// baseline (350.765 us; speedup 1.0000x reference)
//
#include <hip/hip_runtime.h>

#define T_STEPS 256
#define HID 40
#define EPB 16
#define NTHR 640
#define AST 136          // state row stride (shorts); 272 B keeps b128 reads 16B-aligned
#define BS2 (16 * AST)   // parity stride (shorts)
#define BUF (2 * BS2)    // per-buffer stride (shorts)

typedef __attribute__((ext_vector_type(8))) short bf16x8;
typedef __attribute__((ext_vector_type(4))) float f32x4;

__device__ __forceinline__ unsigned short bf16_rne(float v) {
    unsigned int x = __float_as_uint(v);
    unsigned int r = x + 0x7FFFu + ((x >> 16) & 1u);
    return (unsigned short)(r >> 16);
}
__device__ __forceinline__ float bf16f(unsigned short h) {
    return __uint_as_float(((unsigned int)h) << 16);
}
__device__ __forceinline__ float sigm(float v)  { return 1.0f / (1.0f + __expf(-v)); }
__device__ __forceinline__ float tanh_f(float v){ return 1.0f - 2.0f / (__expf(2.0f * v) + 1.0f); }

// Weights = A-operand (M=positions), state = B-operand (N=elems); lane (e,q) of
// tile T gets [r_pre, z_pre, nx, nh] of unit 4T+q in its 4 C-regs (r9-r11 verified).
#define MF(A_, B_, C_) C_ = __builtin_amdgcn_mfma_f32_16x16x32_bf16(A_, B_, C_, 0, 0, 0)
#define PINV(v) asm volatile("" : "+v"(v))

// k'-space: [0,2K) interleaved (hi,lo) state pairs vs wh; [2K,3K) hi2 vs wl.
// 3-term split wh*hi + wh*lo + wl*hi (r7-r11 proven, absmax 2e-3). row<0 => 0.
__device__ bf16x8 wfrag(const float* W, int stride, int K, int row, int c, int qrow) {
    bf16x8 f;
    #pragma unroll
    for (int j = 0; j < 8; ++j) f[j] = 0;
    if (row < 0) return f;
    #pragma unroll
    for (int j = 0; j < 8; ++j) {
        const int kp = 32 * c + qrow * 8 + j;
        if (kp < 2 * K) {
            f[j] = (short)bf16_rne(W[row * stride + (kp >> 1)]);
        } else if (kp < 3 * K) {
            const float w = W[row * stride + (kp - 2 * K)];
            const unsigned short hb = bf16_rne(w);
            f[j] = (short)bf16_rne(w - bf16f(hb));
        }
    }
    return f;
}

// r11 lesson: LDS pipe 83% busy; redundant B reads (16 waves x full operand)
// were the wall. This kernel: 10 waves x 2 tiles each -> reads 116->70 b128/step.
// Waves 0-4: layer0 tiles {2w,2w+1}; waves 5-9: layer1 tiles {2(w-5),2(w-5)+1}.
// VGPR ~16 frags+8 staging names; launch_bounds(640,2) caps 256 (no spill cliff).
__global__ __launch_bounds__(NTHR, 2)
void gru2_kernel(const float* __restrict__ x,
                 const float* __restrict__ Wih0, const float* __restrict__ Whh0,
                 const float* __restrict__ bih0, const float* __restrict__ bhh0,
                 const float* __restrict__ Wih1, const float* __restrict__ Whh1,
                 const float* __restrict__ bih1, const float* __restrict__ bhh1,
                 float* __restrict__ out)
{
    // S[buf][parity][elem][k']: buf 0 = h0, 1 = h1, 2 = x
    __shared__ __align__(16) unsigned short S[3][2][EPB][AST];

    const int tid  = threadIdx.x;
    const int wid  = tid >> 6;     // 0..9
    const int l    = tid & 63;
    const int col  = l & 15;       // elem (B n, C col)
    const int qrow = l >> 4;
    const int pm   = l & 15;       // A-frag position row
    const int ps   = pm & 3;       // slot (0=r,1=z,2=nx,3=nh)
    const int pu   = pm >> 2;      // unit-in-tile
    const int e0   = blockIdx.x * EPB;

    const bool isL1 = wid >= 5;
    const int  lw   = isL1 ? wid - 5 : wid;
    const int  TA   = 2 * lw;
    const int  TB   = 2 * lw + 1;

    const float* Whh = isL1 ? Whh1 : Whh0;
    const float* Wih = isL1 ? Wih1 : Wih0;
    const float* bih = isL1 ? bih1 : bih0;
    const float* bhh = isL1 ? bhh1 : bhh0;
    const int WST = isL1 ? 40 : 16;
    const int KX  = isL1 ? 40 : 16;

    // A-row indices for this lane's slots (tiles A and B)
    const int uA = 4 * TA + pu;
    const int rHA = (ps == 2) ? -1 : (ps == 0 ? uA : ps == 1 ? 40 + uA : 80 + uA);
    const int rXA = (ps == 3) ? -1 : (ps == 0 ? uA : ps == 1 ? 40 + uA : 80 + uA);
    const int uB = 4 * TB + pu;
    const int rHB = (ps == 2) ? -1 : (ps == 0 ? uB : ps == 1 ? 40 + uB : 80 + uB);
    const int rXB = (ps == 3) ? -1 : (ps == 0 ? uB : ps == 1 ? 40 + uB : 80 + uB);

    // ---- weight A-frags (16 names) + biases, pinned ----
    bf16x8 FhA0 = wfrag(Whh, 40, 40, rHA, 0, qrow);
    bf16x8 FhA1 = wfrag(Whh, 40, 40, rHA, 1, qrow);
    bf16x8 FhA2 = wfrag(Whh, 40, 40, rHA, 2, qrow);
    bf16x8 FhA3 = wfrag(Whh, 40, 40, rHA, 3, qrow);
    bf16x8 FxA0 = wfrag(Wih, WST, KX, rXA, 0, qrow);
    bf16x8 FxA1 = wfrag(Wih, WST, KX, rXA, 1, qrow);
    bf16x8 FxA2 = wfrag(Wih, WST, KX, rXA, 2, qrow);  // zero for L0 (K=16)
    bf16x8 FxA3 = wfrag(Wih, WST, KX, rXA, 3, qrow);  // zero for L0
    bf16x8 FhB0 = wfrag(Whh, 40, 40, rHB, 0, qrow);
    bf16x8 FhB1 = wfrag(Whh, 40, 40, rHB, 1, qrow);
    bf16x8 FhB2 = wfrag(Whh, 40, 40, rHB, 2, qrow);
    bf16x8 FhB3 = wfrag(Whh, 40, 40, rHB, 3, qrow);
    bf16x8 FxB0 = wfrag(Wih, WST, KX, rXB, 0, qrow);
    bf16x8 FxB1 = wfrag(Wih, WST, KX, rXB, 1, qrow);
    bf16x8 FxB2 = wfrag(Wih, WST, KX, rXB, 2, qrow);  // zero for L0
    bf16x8 FxB3 = wfrag(Wih, WST, KX, rXB, 3, qrow);  // zero for L0

    const int ucA = 4 * TA + qrow;
    float bb0 = bih[ucA] + bhh[ucA];
    float bb1 = bih[40 + ucA] + bhh[40 + ucA];
    float bb2 = bih[80 + ucA];
    float bb3 = bhh[80 + ucA];
    const int ucB = 4 * TB + qrow;
    float bb4 = bih[ucB] + bhh[ucB];
    float bb5 = bih[40 + ucB] + bhh[40 + ucB];
    float bb6 = bih[80 + ucB];
    float bb7 = bhh[80 + ucB];

    PINV(FhA0); PINV(FhA1); PINV(FhA2); PINV(FhA3);
    PINV(FxA0); PINV(FxA1); PINV(FxA2); PINV(FxA3);
    PINV(FhB0); PINV(FhB1); PINV(FhB2); PINV(FhB3);
    PINV(FxB0); PINV(FxB1); PINV(FxB2); PINV(FxB3);
    asm volatile("" : "+v"(bb0), "+v"(bb1), "+v"(bb2), "+v"(bb3));
    asm volatile("" : "+v"(bb4), "+v"(bb5), "+v"(bb6), "+v"(bb7));

    // LDS offsets (shorts)
    const int rd_h = (isL1 ? BUF : 0) + col * AST + qrow * 8;        // self-layer h
    const int rd_x = (isL1 ? 0 : 2 * BUF) + col * AST + qrow * 8;    // input: h0 or x
    const int wr_b = (isL1 ? BUF : 0) + col * AST;
    unsigned short* Sb = &S[0][0][0][0];
    float hA_ = 0.f, hB_ = 0.f;

#define GATE_WB(U, H) { \
    const float r_ = sigm(c[0]); \
    const float z_ = sigm(c[1]); \
    const float n_ = tanh_f(c[2] + r_ * c[3]); \
    H = (1.0f - z_) * n_ + z_ * H; \
    const unsigned short hb_ = bf16_rne(H); \
    const unsigned short lb_ = bf16_rne(H - bf16f(hb_)); \
    *(unsigned int*)(Sb + wr_b + wo + 2 * (U)) = (unsigned int)hb_ | ((unsigned int)lb_ << 16); \
    (Sb + wr_b + wo)[80 + (U)] = hb_; }

    // ---- init: zero ALL of S (pads must stay 0), stage x[0], preload x[1] ----
    for (int idx = tid; idx < 3 * BUF; idx += NTHR) Sb[idx] = 0;
    __syncthreads();
    const bool xth = tid < 256;
    const int xe = tid >> 4, xk = tid & 15;
    const float* xrow = x + (size_t)(e0 + xe) * (T_STEPS * 16) + xk;
    float xold = 0.f;
    if (xth) {
        const float v = xrow[0];
        const unsigned short hb = bf16_rne(v);
        const unsigned short lb = bf16_rne(v - bf16f(hb));
        *(unsigned int*)(Sb + 2 * BUF + xe * AST + 2 * xk) = (unsigned int)hb | ((unsigned int)lb << 16);
        (Sb + 2 * BUF + xe * AST)[32 + xk] = hb;
        xold = xrow[16];
    }
    __syncthreads();

    for (int t = 0; t <= T_STEPS; ++t) {
        const int ro = (t & 1) * BS2;   // read parity
        const int wo = BS2 - ro;        // write parity

        float xnew = 0.f;
        if (xth && t + 2 < T_STEPS) xnew = xrow[(t + 2) * 16];

        // shared operand reads (once per wave, reused by both tiles)
        const bf16x8 SH0 = *(const bf16x8*)(Sb + rd_h + ro);
        const bf16x8 SH1 = *(const bf16x8*)(Sb + rd_h + ro + 32);
        const bf16x8 SH2 = *(const bf16x8*)(Sb + rd_h + ro + 64);
        const bf16x8 SH3 = *(const bf16x8*)(Sb + rd_h + ro + 96);
        const bf16x8 SX0 = *(const bf16x8*)(Sb + rd_x + ro);
        const bf16x8 SX1 = *(const bf16x8*)(Sb + rd_x + ro + 32);

        if (!isL1) {
            const bool active = (t < T_STEPS);
            f32x4 c = (f32x4){bb0, bb1, bb2, bb3};
            f32x4 d = (f32x4){bb4, bb5, bb6, bb7};
            MF(FhA0, SH0, c); MF(FhB0, SH0, d);
            MF(FhA1, SH1, c); MF(FhB1, SH1, d);
            MF(FhA2, SH2, c); MF(FhB2, SH2, d);
            MF(FhA3, SH3, c); MF(FhB3, SH3, d);
            MF(FxA0, SX0, c); MF(FxB0, SX0, d);
            MF(FxA1, SX1, c); MF(FxB1, SX1, d);
            if (active) {
                GATE_WB(ucA, hA_);
                c = d;
                GATE_WB(ucB, hB_);
            }
        } else {
            const bf16x8 SX2 = *(const bf16x8*)(Sb + rd_x + ro + 64);
            const bf16x8 SX3 = *(const bf16x8*)(Sb + rd_x + ro + 96);
            f32x4 c = (f32x4){bb0, bb1, bb2, bb3};
            f32x4 d = (f32x4){bb4, bb5, bb6, bb7};
            MF(FhA0, SH0, c); MF(FhB0, SH0, d);
            MF(FhA1, SH1, c); MF(FhB1, SH1, d);
            MF(FhA2, SH2, c); MF(FhB2, SH2, d);
            MF(FhA3, SH3, c); MF(FhB3, SH3, d);
            MF(FxA0, SX0, c); MF(FxB0, SX0, d);
            MF(FxA1, SX1, c); MF(FxB1, SX1, d);
            MF(FxA2, SX2, c); MF(FxB2, SX2, d);
            MF(FxA3, SX3, c); MF(FxB3, SX3, d);
            if (t > 0) {
                GATE_WB(ucA, hA_);
                c = d;
                GATE_WB(ucB, hB_);
            }
        }

        // stage x[t+1] into the write parity
        if (xth && t < T_STEPS - 1) {
            const unsigned short hb = bf16_rne(xold);
            const unsigned short lb = bf16_rne(xold - bf16f(hb));
            *(unsigned int*)(Sb + 2 * BUF + xe * AST + wo + 2 * xk) =
                (unsigned int)hb | ((unsigned int)lb << 16);
            (Sb + 2 * BUF + xe * AST + wo)[32 + xk] = hb;
        }
        xold = xnew;
        __syncthreads();   // single barrier: write parity becomes next read parity
    }

    // ---- h1[255] straight from registers (5 L1 waves x 2 tiles x 4 units = 40) ----
    if (isL1) {
        out[(size_t)(e0 + col) * HID + ucA] = hA_;
        out[(size_t)(e0 + col) * HID + ucB] = hB_;
    }
}

extern "C" void kernel_launch(void* const* d_in, const int* in_sizes, int n_in,
                              void* d_out, int out_size, void* d_ws, size_t ws_size,
                              hipStream_t stream) {
    const float* x    = (const float*)d_in[0];
    const float* Wih0 = (const float*)d_in[1];
    const float* Whh0 = (const float*)d_in[2];
    const float* bih0 = (const float*)d_in[3];
    const float* bhh0 = (const float*)d_in[4];
    const float* Wih1 = (const float*)d_in[5];
    const float* Whh1 = (const float*)d_in[6];
    const float* bih1 = (const float*)d_in[7];
    const float* bhh1 = (const float*)d_in[8];
    float* out = (float*)d_out;

    dim3 grid(4096 / EPB), block(NTHR);
    hipLaunchKernelGGL(gru2_kernel, grid, block, 0, stream,
                       x, Wih0, Whh0, bih0, bhh0, Wih1, Whh1, bih1, bhh1, out);
}

// Round 13
// 320.900 us; speedup vs baseline: 1.0931x; 1.0931x over previous
//
#include <hip/hip_runtime.h>

#define T_STEPS 256
#define HID 40
#define EPB 16
#define NTHR 1024
#define AST 136          // state row stride (shorts); 272B: col*68dw -> 8-lane phases conflict-free
#define BS2 (16 * AST)   // parity stride (shorts)
#define BUF (2 * BS2)    // per-buffer stride (shorts)

typedef __attribute__((ext_vector_type(8))) short bf16x8;
typedef __attribute__((ext_vector_type(4))) float f32x4;

__device__ __forceinline__ unsigned short bf16_rne(float v) {
    unsigned int x = __float_as_uint(v);
    unsigned int r = x + 0x7FFFu + ((x >> 16) & 1u);
    return (unsigned short)(r >> 16);
}
__device__ __forceinline__ float bf16f(unsigned short h) {
    return __uint_as_float(((unsigned int)h) << 16);
}
__device__ __forceinline__ float sigm(float v)  { return 1.0f / (1.0f + __expf(-v)); }
__device__ __forceinline__ float tanh_f(float v){ return 1.0f - 2.0f / (__expf(2.0f * v) + 1.0f); }

// Weights = A-operand (M=positions), state = B-operand (N=elems); lane (e,q) of
// tile T gets [r_pre, z_pre, nx, nh] of unit 4T+q in its 4 C-regs (r9-r12 verified).
#define MF(A_, B_, C_) C_ = __builtin_amdgcn_mfma_f32_16x16x32_bf16(A_, B_, C_, 0, 0, 0)
#define PINV(v) asm volatile("" : "+v"(v))

// 2-TERM split (r13 change): state = interleaved (hi,lo) pairs, weight = wh
// duplicated; computes wh*hi + wh*lo. Drops r7-r12's third wl*hi term
// (~2^-9 relative) -- precision gamble vs 1.17e-2 threshold. K'=2K (80 for
// K=40 -> 3 chunks; 32 for K=16 -> 1 chunk). row<0 => zero frag.
__device__ bf16x8 wfrag(const float* W, int stride, int K, int row, int c, int qrow) {
    bf16x8 f;
    #pragma unroll
    for (int j = 0; j < 8; ++j) f[j] = 0;
    if (row < 0) return f;
    #pragma unroll
    for (int j = 0; j < 8; ++j) {
        const int kp = 32 * c + qrow * 8 + j;
        if (kp < 2 * K) f[j] = (short)bf16_rne(W[row * stride + (kp >> 1)]);
    }
    return f;
}

// x float4 -> B-frag (hi,lo interleaved), register-only (x never touches LDS)
#define XCONV(D, V) { \
    unsigned short th_; \
    th_ = bf16_rne((V).x); D[0] = (short)th_; D[1] = (short)bf16_rne((V).x - bf16f(th_)); \
    th_ = bf16_rne((V).y); D[2] = (short)th_; D[3] = (short)bf16_rne((V).y - bf16f(th_)); \
    th_ = bf16_rne((V).z); D[4] = (short)th_; D[5] = (short)bf16_rne((V).z - bf16f(th_)); \
    th_ = bf16_rne((V).w); D[6] = (short)th_; D[7] = (short)bf16_rne((V).w - bf16f(th_)); }

#define GATE_WB(C, U, H) { \
    const float r_ = sigm(C[0]); \
    const float z_ = sigm(C[1]); \
    const float n_ = tanh_f(C[2] + r_ * C[3]); \
    H = (1.0f - z_) * n_ + z_ * H; \
    const unsigned short hb_ = bf16_rne(H); \
    const unsigned short lb_ = bf16_rne(H - bf16f(hb_)); \
    *(unsigned int*)(Sb + wr_b + wo + 2 * (U)) = (unsigned int)hb_ | ((unsigned int)lb_ << 16); }

// r11/r12 A/B: 16 waves/CU (285us) beats 10 waves (321us) even at 1.7x the LDS
// reads -> keep 16 waves, cut reads+chain instead. Waves 0-5: layer0 (tiles
// 2,2,2,2,1,1; x from global regs); waves 6-15: layer1 (1 tile each).
// Ping-pong parities, 1 barrier/step. Split accumulator chains (2x3-deep).
__global__ __launch_bounds__(NTHR, 4)
void gru2_kernel(const float* __restrict__ x,
                 const float* __restrict__ Wih0, const float* __restrict__ Whh0,
                 const float* __restrict__ bih0, const float* __restrict__ bhh0,
                 const float* __restrict__ Wih1, const float* __restrict__ Whh1,
                 const float* __restrict__ bih1, const float* __restrict__ bhh1,
                 float* __restrict__ out)
{
    // S[buf][parity][elem][k']: buf 0 = h0, 1 = h1 (x is register-resident now)
    __shared__ __align__(16) unsigned short S[2][2][EPB][AST];

    const int tid  = threadIdx.x;
    const int wid  = tid >> 6;     // 0..15
    const int l    = tid & 63;
    const int col  = l & 15;       // elem (B n, C col)
    const int qrow = l >> 4;
    const int pm   = l & 15;       // A-frag position row
    const int ps   = pm & 3;       // slot (0=r,1=z,2=nx,3=nh)
    const int pu   = pm >> 2;      // unit-in-tile
    const int e0   = blockIdx.x * EPB;

    const bool isL1 = wid >= 6;
    const int  NT   = (!isL1 && wid < 4) ? 2 : 1;
    const int  TA   = isL1 ? (wid - 6) : (wid < 4 ? 2 * wid : wid + 4);
    const int  TB   = (NT == 2) ? TA + 1 : TA;
    const bool dB   = (NT != 2);

    const float* Whh = isL1 ? Whh1 : Whh0;
    const float* Wih = isL1 ? Wih1 : Wih0;
    const float* bih = isL1 ? bih1 : bih0;
    const float* bhh = isL1 ? bhh1 : bhh0;

    const int uA = 4 * TA + pu;
    const int rHA = (ps == 2) ? -1 : (ps == 0 ? uA : ps == 1 ? 40 + uA : 80 + uA);
    const int rXA = (ps == 3) ? -1 : (ps == 0 ? uA : ps == 1 ? 40 + uA : 80 + uA);
    const int uB = 4 * TB + pu;
    const int rHB = (dB || ps == 2) ? -1 : (ps == 0 ? uB : ps == 1 ? 40 + uB : 80 + uB);
    const int rXB = (dB || ps == 3) ? -1 : (ps == 0 ? uB : ps == 1 ? 40 + uB : 80 + uB);

    // ---- weight A-frags (8 unified names) + biases, pinned ----
    bf16x8 F0, F1, F2, F3, F4, F5, F6, F7;
    if (!isL1) {
        F0 = wfrag(Whh, 40, 40, rHA, 0, qrow);   // tile A: Whh0 chunks 0-2
        F1 = wfrag(Whh, 40, 40, rHA, 1, qrow);
        F2 = wfrag(Whh, 40, 40, rHA, 2, qrow);
        F3 = wfrag(Wih, 16, 16, rXA, 0, qrow);   // tile A: Wih0 (1 chunk)
        F4 = wfrag(Whh, 40, 40, rHB, 0, qrow);   // tile B
        F5 = wfrag(Whh, 40, 40, rHB, 1, qrow);
        F6 = wfrag(Whh, 40, 40, rHB, 2, qrow);
        F7 = wfrag(Wih, 16, 16, rXB, 0, qrow);
    } else {
        F0 = wfrag(Whh, 40, 40, rHA, 0, qrow);   // Whh1 chunks 0-2
        F1 = wfrag(Whh, 40, 40, rHA, 1, qrow);
        F2 = wfrag(Whh, 40, 40, rHA, 2, qrow);
        F3 = wfrag(Wih, 40, 40, rXA, 0, qrow);   // Wih1 chunks 0-2
        F4 = wfrag(Wih, 40, 40, rXA, 1, qrow);
        F5 = wfrag(Wih, 40, 40, rXA, 2, qrow);
        F6 = wfrag(Whh, 40, 40, -1, 0, qrow);    // dead
        F7 = F6;
    }
    const int ucA = 4 * TA + qrow;
    float bb0 = bih[ucA] + bhh[ucA];
    float bb1 = bih[40 + ucA] + bhh[40 + ucA];
    float bb2 = bih[80 + ucA];
    float bb3 = bhh[80 + ucA];
    const int ucB = 4 * TB + qrow;
    float bb4 = dB ? 0.f : (bih[ucB] + bhh[ucB]);
    float bb5 = dB ? 0.f : (bih[40 + ucB] + bhh[40 + ucB]);
    float bb6 = dB ? 0.f : bih[80 + ucB];
    float bb7 = dB ? 0.f : bhh[80 + ucB];

    PINV(F0); PINV(F1); PINV(F2); PINV(F3);
    PINV(F4); PINV(F5); PINV(F6); PINV(F7);
    asm volatile("" : "+v"(bb0), "+v"(bb1), "+v"(bb2), "+v"(bb3));
    asm volatile("" : "+v"(bb4), "+v"(bb5), "+v"(bb6), "+v"(bb7));

    // LDS offsets (shorts)
    const int rd_h = (isL1 ? BUF : 0) + col * AST + qrow * 8;   // self-layer h
    const int rd_x = col * AST + qrow * 8;                      // h0 (L1 input)
    const int wr_b = (isL1 ? BUF : 0) + col * AST;
    unsigned short* Sb = &S[0][0][0][0];
    float hA_ = 0.f, hB_ = 0.f;

    // ---- x prefetch state (L0 waves only): x[e=col][t][qrow*4..+3] ----
    const float4* xp = (const float4*)(x + (size_t)(e0 + col) * (T_STEPS * 16) + qrow * 4);
    bf16x8 XC;
    #pragma unroll
    for (int j = 0; j < 8; ++j) XC[j] = 0;
    float4 xnf = make_float4(0.f, 0.f, 0.f, 0.f);
    if (!isL1) {
        float4 v0 = xp[0];        // x[0]
        XCONV(XC, v0);
        xnf = xp[4];              // x[1]
    }

    // ---- init: zero both h buffers (pads must stay 0) ----
    for (int idx = tid; idx < 2 * BUF; idx += NTHR) Sb[idx] = 0;
    __syncthreads();

    for (int t = 0; t <= T_STEPS; ++t) {
        const int ro = (t & 1) * BS2;   // read parity
        const int wo = BS2 - ro;        // write parity

        const bf16x8 SH0 = *(const bf16x8*)(Sb + rd_h + ro);
        const bf16x8 SH1 = *(const bf16x8*)(Sb + rd_h + ro + 32);
        const bf16x8 SH2 = *(const bf16x8*)(Sb + rd_h + ro + 64);

        if (!isL1) {
            // kick off global load of x[t+2] (latency spans the whole step)
            const bool ld = (t + 2 < T_STEPS);
            float4 xv = xnf;
            if (ld) xv = xp[4 * (t + 2)];

            const bool active = (t < T_STEPS);
            // tile A: two 2-deep chains
            f32x4 c = (f32x4){bb0, bb1, bb2, bb3};
            MF(F0, SH0, c); MF(F1, SH1, c);
            f32x4 d = (f32x4){0.f, 0.f, 0.f, 0.f};
            MF(F2, SH2, d); MF(F3, XC, d);
            c[0] += d[0]; c[1] += d[1]; c[2] += d[2]; c[3] += d[3];
            if (NT == 2) {
                f32x4 e2 = (f32x4){bb4, bb5, bb6, bb7};
                MF(F4, SH0, e2); MF(F5, SH1, e2);
                f32x4 f2 = (f32x4){0.f, 0.f, 0.f, 0.f};
                MF(F6, SH2, f2); MF(F7, XC, f2);
                e2[0] += f2[0]; e2[1] += f2[1]; e2[2] += f2[2]; e2[3] += f2[3];
                if (active) { GATE_WB(c, ucA, hA_); GATE_WB(e2, ucB, hB_); }
            } else {
                if (active) GATE_WB(c, ucA, hA_);
            }
            // rotate x pipeline: XC <- x[t+1], xnf <- x[t+2]
            XCONV(XC, xnf);
            xnf = xv;
        } else {
            const bf16x8 SX0 = *(const bf16x8*)(Sb + rd_x + ro);
            const bf16x8 SX1 = *(const bf16x8*)(Sb + rd_x + ro + 32);
            const bf16x8 SX2 = *(const bf16x8*)(Sb + rd_x + ro + 64);
            // two 3-deep chains
            f32x4 c = (f32x4){bb0, bb1, bb2, bb3};
            MF(F0, SH0, c); MF(F1, SH1, c); MF(F2, SH2, c);
            f32x4 d = (f32x4){0.f, 0.f, 0.f, 0.f};
            MF(F3, SX0, d); MF(F4, SX1, d); MF(F5, SX2, d);
            c[0] += d[0]; c[1] += d[1]; c[2] += d[2]; c[3] += d[3];
            if (t > 0) GATE_WB(c, ucA, hA_);
        }

        __syncthreads();   // single barrier: write parity becomes next read parity
    }

    // ---- h1[255] straight from registers (10 L1 waves x 4 units = 40) ----
    if (isL1) {
        out[(size_t)(e0 + col) * HID + ucA] = hA_;
    }
}

extern "C" void kernel_launch(void* const* d_in, const int* in_sizes, int n_in,
                              void* d_out, int out_size, void* d_ws, size_t ws_size,
                              hipStream_t stream) {
    const float* x    = (const float*)d_in[0];
    const float* Wih0 = (const float*)d_in[1];
    const float* Whh0 = (const float*)d_in[2];
    const float* bih0 = (const float*)d_in[3];
    const float* bhh0 = (const float*)d_in[4];
    const float* Wih1 = (const float*)d_in[5];
    const float* Whh1 = (const float*)d_in[6];
    const float* bih1 = (const float*)d_in[7];
    const float* bhh1 = (const float*)d_in[8];
    float* out = (float*)d_out;

    dim3 grid(4096 / EPB), block(NTHR);
    hipLaunchKernelGGL(gru2_kernel, grid, block, 0, stream,
                       x, Wih0, Whh0, bih0, bhh0, Wih1, Whh1, bih1, bhh1, out);
}

// Round 14
// 296.611 us; speedup vs baseline: 1.1826x; 1.0819x over previous
//
#include <hip/hip_runtime.h>

#define T_STEPS 256
#define HID 40
#define EPB 16
#define NTHR 1024
#define HAST 104         // h row stride (shorts): 52 dw -> 8 distinct bank phases / 8 lanes
#define XAST 40          // x row stride (shorts): 20 dw -> distinct phases
#define HPAR (16 * HAST) // 1664 shorts per h parity
#define XPAR (16 * XAST) // 640 shorts per x parity
#define OH0 0
#define OH1 (2 * HPAR)
#define OX  (4 * HPAR)
#define STOT (4 * HPAR + 2 * XPAR)   // 7936 shorts = 15872 B

typedef __attribute__((ext_vector_type(8))) short bf16x8;
typedef __attribute__((ext_vector_type(4))) float f32x4;

__device__ __forceinline__ unsigned short bf16_rne(float v) {
    unsigned int x = __float_as_uint(v);
    unsigned int r = x + 0x7FFFu + ((x >> 16) & 1u);
    return (unsigned short)(r >> 16);
}
__device__ __forceinline__ float bf16f(unsigned short h) {
    return __uint_as_float(((unsigned int)h) << 16);
}
__device__ __forceinline__ float sigm(float v)  { return 1.0f / (1.0f + __expf(-v)); }
__device__ __forceinline__ float tanh_f(float v){ return 1.0f - 2.0f / (__expf(2.0f * v) + 1.0f); }

#define MF(A_, B_, C_) C_ = __builtin_amdgcn_mfma_f32_16x16x32_bf16(A_, B_, C_, 0, 0, 0)
#define PINV(v) asm volatile("" : "+v"(v))

// 2-term split (r13-proven, absmax 2e-3): state = interleaved (hi,lo) pairs,
// weight duplicated per pair; computes wh*hi + wh*lo. K'=2K. row<0 => 0.
__device__ bf16x8 wfrag(const float* W, int stride, int K, int row, int c, int qrow) {
    bf16x8 f;
    #pragma unroll
    for (int j = 0; j < 8; ++j) f[j] = 0;
    if (row < 0) return f;
    #pragma unroll
    for (int j = 0; j < 8; ++j) {
        const int kp = 32 * c + qrow * 8 + j;
        if (kp < 2 * K) f[j] = (short)bf16_rne(W[row * stride + (kp >> 1)]);
    }
    return f;
}

// r13 post-mortem: VALU-issue-bound (72%). Cuts here: (1) x staged once in LDS
// (r13's per-L0-wave XCONV was 6x-redundant); (2) 2-step unroll -> compile-time
// parity offsets, zero address VALU; (3) single MFMA chain, bias f32x4 as the
// first MFMA's C operand (no init movs, no merges). Structure else = r13:
// 16 waves (0-5 L0 tiles {2,2,2,2,1,1}; 6-15 L1 1 tile), ping-pong, 1 barrier.
__global__ __launch_bounds__(NTHR, 4)
void gru2_kernel(const float* __restrict__ x,
                 const float* __restrict__ Wih0, const float* __restrict__ Whh0,
                 const float* __restrict__ bih0, const float* __restrict__ bhh0,
                 const float* __restrict__ Wih1, const float* __restrict__ Whh1,
                 const float* __restrict__ bih1, const float* __restrict__ bhh1,
                 float* __restrict__ out)
{
    __shared__ __align__(16) unsigned short S[STOT];

    const int tid  = threadIdx.x;
    const int wid  = tid >> 6;     // 0..15
    const int l    = tid & 63;
    const int col  = l & 15;       // elem (B n, C col)
    const int qrow = l >> 4;
    const int pm   = l & 15;       // A-frag position row
    const int ps   = pm & 3;       // slot (0=r,1=z,2=nx,3=nh)
    const int pu   = pm >> 2;      // unit-in-tile
    const int e0   = blockIdx.x * EPB;

    const bool isL1 = wid >= 6;
    const int  NT   = (!isL1 && wid < 4) ? 2 : 1;
    const int  TA   = isL1 ? (wid - 6) : (wid < 4 ? 2 * wid : wid + 4);
    const int  TB   = (NT == 2) ? TA + 1 : TA;
    const bool dB   = (NT != 2);

    const float* Whh = isL1 ? Whh1 : Whh0;
    const float* Wih = isL1 ? Wih1 : Wih0;
    const float* bih = isL1 ? bih1 : bih0;
    const float* bhh = isL1 ? bhh1 : bhh0;

    const int uA = 4 * TA + pu;
    const int rHA = (ps == 2) ? -1 : (ps == 0 ? uA : ps == 1 ? 40 + uA : 80 + uA);
    const int rXA = (ps == 3) ? -1 : (ps == 0 ? uA : ps == 1 ? 40 + uA : 80 + uA);
    const int uB = 4 * TB + pu;
    const int rHB = (dB || ps == 2) ? -1 : (ps == 0 ? uB : ps == 1 ? 40 + uB : 80 + uB);
    const int rXB = (dB || ps == 3) ? -1 : (ps == 0 ? uB : ps == 1 ? 40 + uB : 80 + uB);

    // ---- weight A-frags (8 unified names) + bias vectors, pinned ----
    bf16x8 F0, F1, F2, F3, F4, F5, F6, F7;
    if (!isL1) {
        F0 = wfrag(Whh, 40, 40, rHA, 0, qrow);
        F1 = wfrag(Whh, 40, 40, rHA, 1, qrow);
        F2 = wfrag(Whh, 40, 40, rHA, 2, qrow);
        F3 = wfrag(Wih, 16, 16, rXA, 0, qrow);
        F4 = wfrag(Whh, 40, 40, rHB, 0, qrow);
        F5 = wfrag(Whh, 40, 40, rHB, 1, qrow);
        F6 = wfrag(Whh, 40, 40, rHB, 2, qrow);
        F7 = wfrag(Wih, 16, 16, rXB, 0, qrow);
    } else {
        F0 = wfrag(Whh, 40, 40, rHA, 0, qrow);
        F1 = wfrag(Whh, 40, 40, rHA, 1, qrow);
        F2 = wfrag(Whh, 40, 40, rHA, 2, qrow);
        F3 = wfrag(Wih, 40, 40, rXA, 0, qrow);
        F4 = wfrag(Wih, 40, 40, rXA, 1, qrow);
        F5 = wfrag(Wih, 40, 40, rXA, 2, qrow);
        F6 = wfrag(Whh, 40, 40, -1, 0, qrow);
        F7 = F6;
    }
    const int ucA = 4 * TA + qrow;
    const int ucB = 4 * TB + qrow;
    f32x4 BBA, BBB;
    BBA[0] = bih[ucA] + bhh[ucA];
    BBA[1] = bih[40 + ucA] + bhh[40 + ucA];
    BBA[2] = bih[80 + ucA];
    BBA[3] = bhh[80 + ucA];
    BBB[0] = dB ? 0.f : (bih[ucB] + bhh[ucB]);
    BBB[1] = dB ? 0.f : (bih[40 + ucB] + bhh[40 + ucB]);
    BBB[2] = dB ? 0.f : bih[80 + ucB];
    BBB[3] = dB ? 0.f : bhh[80 + ucB];

    PINV(F0); PINV(F1); PINV(F2); PINV(F3);
    PINV(F4); PINV(F5); PINV(F6); PINV(F7);
    PINV(BBA); PINV(BBB);

    // LDS base offsets (shorts); parity added as compile-time immediate in BODY
    const int rd_h = (isL1 ? OH1 : OH0) + col * HAST + qrow * 8;
    const int rd_x = isL1 ? (OH0 + col * HAST + qrow * 8)
                          : (OX  + col * XAST + qrow * 8);
    const int wr_b = (isL1 ? OH1 : OH0) + col * HAST;
    unsigned short* Sb = &S[0];
    float hA_ = 0.f, hB_ = 0.f;

#define GATE_WB(C, U, H, WPH_) { \
    const float r_ = sigm(C[0]); \
    const float z_ = sigm(C[1]); \
    const float n_ = tanh_f(C[2] + r_ * C[3]); \
    H = (1.0f - z_) * n_ + z_ * H; \
    const unsigned short hb_ = bf16_rne(H); \
    const unsigned short lb_ = bf16_rne(H - bf16f(hb_)); \
    *(unsigned int*)(Sb + wr_b + (WPH_) + 2 * (U)) = (unsigned int)hb_ | ((unsigned int)lb_ << 16); }

    // ---- init: zero all of S (pads must stay 0), stage x[0], preload x[1] ----
    for (int idx = tid; idx < STOT; idx += NTHR) Sb[idx] = 0;
    __syncthreads();
    const bool xth = tid < 256;
    const int xe = tid >> 4, xk = tid & 15;
    const float* xrow = x + (size_t)(e0 + xe) * (T_STEPS * 16) + xk;
    float xold = 0.f;
    if (xth) {
        const float v = xrow[0];
        const unsigned short hb = bf16_rne(v);
        const unsigned short lb = bf16_rne(v - bf16f(hb));
        *(unsigned int*)(Sb + OX + xe * XAST + 2 * xk) = (unsigned int)hb | ((unsigned int)lb << 16);
        xold = xrow[16];
    }
    __syncthreads();

#define BODY(RP) { \
    float xnew = 0.f; \
    if (xth && t + 2 < T_STEPS) xnew = xrow[(t + 2) * 16]; \
    const bf16x8 SH0 = *(const bf16x8*)(Sb + rd_h + (RP) * HPAR); \
    const bf16x8 SH1 = *(const bf16x8*)(Sb + rd_h + (RP) * HPAR + 32); \
    const bf16x8 SH2 = *(const bf16x8*)(Sb + rd_h + (RP) * HPAR + 64); \
    if (!isL1) { \
        if (t < T_STEPS) { \
            const bf16x8 SX0 = *(const bf16x8*)(Sb + rd_x + (RP) * XPAR); \
            f32x4 c = __builtin_amdgcn_mfma_f32_16x16x32_bf16(F0, SH0, BBA, 0, 0, 0); \
            MF(F1, SH1, c); MF(F2, SH2, c); MF(F3, SX0, c); \
            GATE_WB(c, ucA, hA_, (1 - (RP)) * HPAR); \
            if (NT == 2) { \
                f32x4 d = __builtin_amdgcn_mfma_f32_16x16x32_bf16(F4, SH0, BBB, 0, 0, 0); \
                MF(F5, SH1, d); MF(F6, SH2, d); MF(F7, SX0, d); \
                GATE_WB(d, ucB, hB_, (1 - (RP)) * HPAR); \
            } \
        } \
    } else { \
        const bf16x8 SX0 = *(const bf16x8*)(Sb + rd_x + (RP) * HPAR); \
        const bf16x8 SX1 = *(const bf16x8*)(Sb + rd_x + (RP) * HPAR + 32); \
        const bf16x8 SX2 = *(const bf16x8*)(Sb + rd_x + (RP) * HPAR + 64); \
        f32x4 c = __builtin_amdgcn_mfma_f32_16x16x32_bf16(F0, SH0, BBA, 0, 0, 0); \
        MF(F1, SH1, c); MF(F2, SH2, c); \
        MF(F3, SX0, c); MF(F4, SX1, c); MF(F5, SX2, c); \
        if (t > 0) GATE_WB(c, ucA, hA_, (1 - (RP)) * HPAR); \
    } \
    if (xth && t < T_STEPS - 1) { \
        const unsigned short hb = bf16_rne(xold); \
        const unsigned short lb = bf16_rne(xold - bf16f(hb)); \
        *(unsigned int*)(Sb + OX + xe * XAST + (1 - (RP)) * XPAR + 2 * xk) = \
            (unsigned int)hb | ((unsigned int)lb << 16); \
    } \
    xold = xnew; \
    ++t; \
    __syncthreads(); }

    int t = 0;
    #pragma unroll 1
    for (int it = 0; it < 128; ++it) {
        BODY(0)
        BODY(1)
    }
    BODY(0)   // t = 256: L1 finishes h1[255]; L0 inactive

    // ---- h1[255] straight from registers (10 L1 waves x 4 units = 40) ----
    if (isL1) {
        out[(size_t)(e0 + col) * HID + ucA] = hA_;
    }
}

extern "C" void kernel_launch(void* const* d_in, const int* in_sizes, int n_in,
                              void* d_out, int out_size, void* d_ws, size_t ws_size,
                              hipStream_t stream) {
    const float* x    = (const float*)d_in[0];
    const float* Wih0 = (const float*)d_in[1];
    const float* Whh0 = (const float*)d_in[2];
    const float* bih0 = (const float*)d_in[3];
    const float* bhh0 = (const float*)d_in[4];
    const float* Wih1 = (const float*)d_in[5];
    const float* Whh1 = (const float*)d_in[6];
    const float* bih1 = (const float*)d_in[7];
    const float* bhh1 = (const float*)d_in[8];
    float* out = (float*)d_out;

    dim3 grid(4096 / EPB), block(NTHR);
    hipLaunchKernelGGL(gru2_kernel, grid, block, 0, stream,
                       x, Wih0, Whh0, bih0, bhh0, Wih1, Whh1, bih1, bhh1, out);
}

// Round 15
// 270.062 us; speedup vs baseline: 1.2988x; 1.0983x over previous
//
#include <hip/hip_runtime.h>

#define T_STEPS 256
#define HID 40
#define EPB 16
#define NTHR 1024
#define R0 72            // L0 row stride (shorts): [h0(40) | x(16) | pad]
#define R1 104           // L1 row stride (shorts): [h1(40) | h0(40) | pad]
#define P0 (16 * R0)     // L0 parity stride = 1152 shorts
#define P1 (16 * R1)     // L1 parity stride = 1664 shorts
#define OL1 (2 * P0)     // L1 region offset = 2304 shorts
#define STOT (2 * P0 + 2 * P1)   // 5632 shorts = 11264 B

typedef __attribute__((ext_vector_type(8))) short bf16x8;
typedef __attribute__((ext_vector_type(4))) float f32x4;

__device__ __forceinline__ unsigned short bf16_rne(float v) {
    unsigned int x = __float_as_uint(v);
    unsigned int r = x + 0x7FFFu + ((x >> 16) & 1u);
    return (unsigned short)(r >> 16);
}
__device__ __forceinline__ float sigm(float v)  { return 1.0f / (1.0f + __expf(-v)); }
__device__ __forceinline__ float tanh_f(float v){ return 1.0f - 2.0f / (__expf(2.0f * v) + 1.0f); }

#define MF(A_, B_, C_) C_ = __builtin_amdgcn_mfma_f32_16x16x32_bf16(A_, B_, C_, 0, 0, 0)
#define PINV(v) asm volatile("" : "+v"(v))

// r15: 1-TERM bf16 state (no lo compensation; r7-r14's absmax was pinned at
// 2^-9 independent of split order -> the split wasn't the floor) over UNIFIED
// K-concat rows [h_self | input]. r/z slots fuse W_hr*h + W_ir*x in one chain.
// A-frag element at k' = 32c + 8qrow + j: k'<40 -> Whh[rh][k'] (slots r,z,nh);
// 40<=k'<40+KX -> Wih[rx][k'-40] (slots r,z,nx); else 0.
__device__ bf16x8 afrag(const float* Whh, const float* Wih, int KX,
                        int rh, int rx, int c, int qrow) {
    bf16x8 f;
    #pragma unroll
    for (int j = 0; j < 8; ++j) f[j] = 0;
    #pragma unroll
    for (int j = 0; j < 8; ++j) {
        const int k = 32 * c + qrow * 8 + j;
        if (k < 40) {
            if (rh >= 0) f[j] = (short)bf16_rne(Whh[rh * 40 + k]);
        } else if (k < 40 + KX) {
            if (rx >= 0) f[j] = (short)bf16_rne(Wih[rx * KX + (k - 40)]);
        }
    }
    return f;
}

// Structure from r13/r14 (proven): 16 waves, waves 0-5 L0 (tiles 2,2,2,2,1,1),
// waves 6-15 L1 (1 tile); ping-pong parities, 2-step unroll (compile-time
// offsets), bias f32x4 as first MFMA's C operand, 1 barrier/step, layer skew
// (step t: L0 computes h0[t], L1 computes h1[t-1]).
__global__ __launch_bounds__(NTHR, 4)
void gru2_kernel(const float* __restrict__ x,
                 const float* __restrict__ Wih0, const float* __restrict__ Whh0,
                 const float* __restrict__ bih0, const float* __restrict__ bhh0,
                 const float* __restrict__ Wih1, const float* __restrict__ Whh1,
                 const float* __restrict__ bih1, const float* __restrict__ bhh1,
                 float* __restrict__ out)
{
    __shared__ __align__(16) unsigned short S[STOT];

    const int tid  = threadIdx.x;
    const int wid  = tid >> 6;     // 0..15
    const int l    = tid & 63;
    const int col  = l & 15;       // elem (B n, C col)
    const int qrow = l >> 4;
    const int pm   = l & 15;       // A-frag position row
    const int ps   = pm & 3;       // slot (0=r,1=z,2=nx,3=nh)
    const int pu   = pm >> 2;      // unit-in-tile
    const int e0   = blockIdx.x * EPB;

    const bool isL1 = wid >= 6;
    const int  NT   = (!isL1 && wid < 4) ? 2 : 1;
    const int  TA   = isL1 ? (wid - 6) : (wid < 4 ? 2 * wid : wid + 4);
    const int  TB   = (NT == 2) ? TA + 1 : TA;
    const bool dB   = (NT != 2);

    const float* Whh = isL1 ? Whh1 : Whh0;
    const float* Wih = isL1 ? Wih1 : Wih0;
    const float* bih = isL1 ? bih1 : bih0;
    const float* bhh = isL1 ? bhh1 : bhh0;
    const int KX = isL1 ? 40 : 16;

    const int uA = 4 * TA + pu;
    const int rhA = (ps == 2) ? -1 : (ps == 0 ? uA : ps == 1 ? 40 + uA : 80 + uA);
    const int rxA = (ps == 3) ? -1 : (ps == 0 ? uA : ps == 1 ? 40 + uA : 80 + uA);
    const int uB = 4 * TB + pu;
    const int rhB = (dB || ps == 2) ? -1 : (ps == 0 ? uB : ps == 1 ? 40 + uB : 80 + uB);
    const int rxB = (dB || ps == 3) ? -1 : (ps == 0 ? uB : ps == 1 ? 40 + uB : 80 + uB);

    // ---- weight A-frags (4 unified names) + bias vectors, pinned ----
    // L0: F0,F1 = tile A chunks 0,1 ; F2,F3 = tile B chunks 0,1  (K'=56)
    // L1: F0,F1,F2 = tile A chunks 0,1,2 ; F3 dead                (K'=80)
    bf16x8 F0, F1, F2, F3;
    if (!isL1) {
        F0 = afrag(Whh, Wih, KX, rhA, rxA, 0, qrow);
        F1 = afrag(Whh, Wih, KX, rhA, rxA, 1, qrow);
        F2 = afrag(Whh, Wih, KX, rhB, rxB, 0, qrow);
        F3 = afrag(Whh, Wih, KX, rhB, rxB, 1, qrow);
    } else {
        F0 = afrag(Whh, Wih, KX, rhA, rxA, 0, qrow);
        F1 = afrag(Whh, Wih, KX, rhA, rxA, 1, qrow);
        F2 = afrag(Whh, Wih, KX, rhA, rxA, 2, qrow);
        F3 = afrag(Whh, Wih, KX, -1, -1, 0, qrow);
    }
    const int ucA = 4 * TA + qrow;
    const int ucB = 4 * TB + qrow;
    f32x4 BBA, BBB;
    BBA[0] = bih[ucA] + bhh[ucA];
    BBA[1] = bih[40 + ucA] + bhh[40 + ucA];
    BBA[2] = bih[80 + ucA];
    BBA[3] = bhh[80 + ucA];
    BBB[0] = dB ? 0.f : (bih[ucB] + bhh[ucB]);
    BBB[1] = dB ? 0.f : (bih[40 + ucB] + bhh[40 + ucB]);
    BBB[2] = dB ? 0.f : bih[80 + ucB];
    BBB[3] = dB ? 0.f : bhh[80 + ucB];

    PINV(F0); PINV(F1); PINV(F2); PINV(F3);
    PINV(BBA); PINV(BBB);

    // LDS base offsets (shorts); parity added as compile-time immediate in BODY
    const int rdl = isL1 ? (OL1 + col * R1 + qrow * 8) : (col * R0 + qrow * 8);
    const int w0b = col * R0;            // L0 self-row base
    const int w1b = OL1 + col * R1;      // L1 row base
    unsigned short* Sb = &S[0];
    float hA_ = 0.f, hB_ = 0.f;

    // L0 task: write h0' into BOTH rows (self + L1's input span at +40)
#define GATE_L0(C, U, H, WP_) { \
    const float r_ = sigm(C[0]); \
    const float z_ = sigm(C[1]); \
    const float n_ = tanh_f(C[2] + r_ * C[3]); \
    H = (1.0f - z_) * n_ + z_ * H; \
    const unsigned short hb_ = bf16_rne(H); \
    Sb[w0b + (WP_) * P0 + (U)] = hb_; \
    Sb[w1b + (WP_) * P1 + 40 + (U)] = hb_; }
#define GATE_L1(C, U, H, WP_) { \
    const float r_ = sigm(C[0]); \
    const float z_ = sigm(C[1]); \
    const float n_ = tanh_f(C[2] + r_ * C[3]); \
    H = (1.0f - z_) * n_ + z_ * H; \
    Sb[w1b + (WP_) * P1 + (U)] = bf16_rne(H); }

    // ---- init: zero all of S (pads must stay 0), stage x[0], preload x[1] ----
    for (int idx = tid; idx < STOT; idx += NTHR) Sb[idx] = 0;
    __syncthreads();
    const bool xth = tid < 256;
    const int xe = tid >> 4, xk = tid & 15;
    const float* xrow = x + (size_t)(e0 + xe) * (T_STEPS * 16) + xk;
    float xold = 0.f;
    if (xth) {
        Sb[xe * R0 + 40 + xk] = bf16_rne(xrow[0]);
        xold = xrow[16];
    }
    __syncthreads();

#define BODY(RP) { \
    float xnew = 0.f; \
    if (xth && t + 2 < T_STEPS) xnew = xrow[(t + 2) * 16]; \
    if (!isL1) { \
        const bf16x8 S0 = *(const bf16x8*)(Sb + rdl + (RP) * P0); \
        const bf16x8 S1 = *(const bf16x8*)(Sb + rdl + (RP) * P0 + 32); \
        if (t < T_STEPS) { \
            f32x4 c = __builtin_amdgcn_mfma_f32_16x16x32_bf16(F0, S0, BBA, 0, 0, 0); \
            MF(F1, S1, c); \
            GATE_L0(c, ucA, hA_, (1 - (RP))); \
            if (NT == 2) { \
                f32x4 d = __builtin_amdgcn_mfma_f32_16x16x32_bf16(F2, S0, BBB, 0, 0, 0); \
                MF(F3, S1, d); \
                GATE_L0(d, ucB, hB_, (1 - (RP))); \
            } \
        } \
    } else { \
        const bf16x8 S0 = *(const bf16x8*)(Sb + rdl + (RP) * P1); \
        const bf16x8 S1 = *(const bf16x8*)(Sb + rdl + (RP) * P1 + 32); \
        const bf16x8 S2 = *(const bf16x8*)(Sb + rdl + (RP) * P1 + 64); \
        f32x4 c = __builtin_amdgcn_mfma_f32_16x16x32_bf16(F0, S0, BBA, 0, 0, 0); \
        MF(F1, S1, c); MF(F2, S2, c); \
        if (t > 0) GATE_L1(c, ucA, hA_, (1 - (RP))); \
    } \
    if (xth && t < T_STEPS - 1) { \
        Sb[xe * R0 + (1 - (RP)) * P0 + 40 + xk] = bf16_rne(xold); \
    } \
    xold = xnew; \
    ++t; \
    __syncthreads(); }

    int t = 0;
    #pragma unroll 1
    for (int it = 0; it < 128; ++it) {
        BODY(0)
        BODY(1)
    }
    BODY(0)   // t = 256: L1 finishes h1[255]; L0 inactive

    // ---- h1[255] straight from registers (10 L1 waves x 4 units = 40) ----
    if (isL1) {
        out[(size_t)(e0 + col) * HID + ucA] = hA_;
    }
}

extern "C" void kernel_launch(void* const* d_in, const int* in_sizes, int n_in,
                              void* d_out, int out_size, void* d_ws, size_t ws_size,
                              hipStream_t stream) {
    const float* x    = (const float*)d_in[0];
    const float* Wih0 = (const float*)d_in[1];
    const float* Whh0 = (const float*)d_in[2];
    const float* bih0 = (const float*)d_in[3];
    const float* bhh0 = (const float*)d_in[4];
    const float* Wih1 = (const float*)d_in[5];
    const float* Whh1 = (const float*)d_in[6];
    const float* bih1 = (const float*)d_in[7];
    const float* bhh1 = (const float*)d_in[8];
    float* out = (float*)d_out;

    dim3 grid(4096 / EPB), block(NTHR);
    hipLaunchKernelGGL(gru2_kernel, grid, block, 0, stream,
                       x, Wih0, Whh0, bih0, bhh0, Wih1, Whh1, bih1, bhh1, out);
}